// Round 1
// baseline (190.569 us; speedup 1.0000x reference)
//
#include <hip/hip_runtime.h>
#include <hip/hip_fp16.h>
#include <math.h>

#define NB   16     // batch
#define IMG  128    // input image side
#define NANG 300
#define NDET 300
#define WB   148    // canvas live box: x,y in [76,224)

typedef _Float16 v2h __attribute__((ext_vector_type(2)));

// Gaussian taps: sigma_img -> 2^(-d^2/2); sigma_att -> 2^(-d^2/8). f64 normalize, f32 cast.
__device__ __constant__ float KE[9] = {
  (float)(0.00390625            / 3.0104144100214136),
  (float)(0.04419417382415922   / 3.0104144100214136),
  (float)(0.25                  / 3.0104144100214136),
  (float)(0.7071067811865476    / 3.0104144100214136),
  (float)(1.0                   / 3.0104144100214136),
  (float)(0.7071067811865476    / 3.0104144100214136),
  (float)(0.25                  / 3.0104144100214136),
  (float)(0.04419417382415922   / 3.0104144100214136),
  (float)(0.00390625            / 3.0104144100214136)
};
__device__ __constant__ float KA[17] = {
  (float)(0.00390625            / 6.019333926786741),
  (float)(0.014328188175072987  / 6.019333926786741),
  (float)(0.04419417382415922   / 6.019333926786741),
  (float)(0.11462550540058389   / 6.019333926786741),
  (float)(0.25                  / 6.019333926786741),
  (float)(0.4585020216023356    / 6.019333926786741),
  (float)(0.7071067811865476    / 6.019333926786741),
  (float)(0.9170040432046712    / 6.019333926786741),
  (float)(1.0                   / 6.019333926786741),
  (float)(0.9170040432046712    / 6.019333926786741),
  (float)(0.7071067811865476    / 6.019333926786741),
  (float)(0.4585020216023356    / 6.019333926786741),
  (float)(0.25                  / 6.019333926786741),
  (float)(0.11462550540058389   / 6.019333926786741),
  (float)(0.04419417382415922   / 6.019333926786741),
  (float)(0.014328188175072987  / 6.019333926786741),
  (float)(0.00390625            / 6.019333926786741)
};

__device__ __forceinline__ unsigned h16(float f) {
  return (unsigned)__half_as_ushort(__float2half_rn(f));
}
__device__ __forceinline__ unsigned pk16u(float a, float b) {
  return __builtin_bit_cast(unsigned, __builtin_amdgcn_cvt_pkrtz(a, b));
}
__device__ __forceinline__ float fdot2(unsigned q, unsigned w, float acc) {
  return __builtin_amdgcn_fdot2(__builtin_bit_cast(v2h, q), __builtin_bit_cast(v2h, w), acc, false);
}

// K1: fused pad+blur -> f16 x-pair canvas over the live box [76,224)^2.
// Q[y'][x'][b] = uint2{ E(y,x)|E(y,x+1)<<16 , A(y,x)|A(y,x+1)<<16 }  (A pre-scaled 0.01).
// NON-duplicated along y (row y0+1 of the bilinear footprint comes from the next
// canvas row at a second SGPR base in k_radon). Canvas = 148*148*16*8B = 2.80 MB,
// fits a 4 MiB per-XCD L2 -> kills the HBM thrash the old 5.6 MB quad canvas had.
// Values bit-identical to the old quad entries (E10 of (y,x) == E00 of (y+1,x)).
__global__ void k_prep(const float* __restrict__ img, const float* __restrict__ att,
                       uint2* __restrict__ Q) {
  __shared__ float sImg[25 * 25];
  __shared__ float sAtt[33 * 33];
  __shared__ float sEi[25 * 17];
  __shared__ float sAi[33 * 17];

  int tid = threadIdx.x;
  int tx = tid & 15, ty = tid >> 4;
  int X0 = blockIdx.x * 16;
  int Y0 = blockIdx.y * 16;
  int b  = blockIdx.z;
  const float* imb = img + b * IMG * IMG;
  const float* atb = att + b * IMG * IMG;
  for (int t = tid; t < 625; t += 256) {
    int r = t / 25, c = t - r * 25;
    int ir = Y0 - 14 + r, ic = X0 - 14 + c;
    bool v = (ir >= 0) & (ir < IMG) & (ic >= 0) & (ic < IMG);
    sImg[t] = v ? imb[ir * IMG + ic] : 0.f;
  }
  for (int t = tid; t < 1089; t += 256) {
    int r = t / 33, c = t - r * 33;
    int ir = Y0 - 18 + r, ic = X0 - 18 + c;
    bool v = (ir >= 0) & (ir < IMG) & (ic >= 0) & (ic < IMG);
    sAtt[t] = v ? atb[ir * IMG + ic] : 0.f;
  }
  __syncthreads();
  for (int t = tid; t < 425; t += 256) {
    int r = t / 17, c = t - r * 17;
    float acc = 0.f;
#pragma unroll
    for (int d = 0; d < 9; ++d) acc = fmaf(KE[d], sImg[r * 25 + c + d], acc);
    sEi[t] = acc;
  }
  for (int t = tid; t < 561; t += 256) {
    int r = t / 17, c = t - r * 17;
    float acc = 0.f;
#pragma unroll
    for (int d = 0; d < 17; ++d) acc = fmaf(KA[d], sAtt[r * 33 + c + d], acc);
    sAi[t] = acc;
  }
  __syncthreads();
  int xc = X0 + tx, yc = Y0 + ty;
  if (xc >= WB || yc >= WB) return;
  float E00 = 0.f, E01 = 0.f;
  float A00 = 0.f, A01 = 0.f;
#pragma unroll
  for (int d = 0; d < 9; ++d) {
    float k = KE[d];
    E00 = fmaf(k, sEi[(ty + d) * 17 + tx],     E00);
    E01 = fmaf(k, sEi[(ty + d) * 17 + tx + 1], E01);
  }
#pragma unroll
  for (int d = 0; d < 17; ++d) {
    float k = KA[d];
    A00 = fmaf(k, sAi[(ty + d) * 17 + tx],     A00);
    A01 = fmaf(k, sAi[(ty + d) * 17 + tx + 1], A01);
  }
  uint2 q;
  q.x = h16(E00) | (h16(E01) << 16);
  q.y = h16(0.01f * A00) | (h16(0.01f * A01) << 16);
  Q[(yc * WB + xc) * NB + b] = q;
}

// K2: radon with wave-local LDS coordinate pipeline, double-buffered across chunks.
// Block 256 = 16 j x 16 b; wave = 4 j x 16 b. Per 16-sample chunk:
//   stage (phase A): each lane computes coords+weights for a DISTINCT (j, i)
//     -> {voff, w0, w1} into the chunk's LDS buffer. Staged ONE CHUNK AHEAD so
//     the LDS write->read round trip hides under the previous chunk's loads+fdot2.
//   consume (phase B): 16 u-steps: broadcast ds_read_b128, one v_add for the
//     32-bit voffset, two saddr-form global_load_dwordx2 (rows y0 / y0+1, two
//     uniform bases P0/P1), 4 fdot2. Each 16-lane group's load = one full 128 B line.
// Coordinate clamp px,py -> [76.5, 222.0] BEFORE floor:
//   * identity for in-chord samples (exact);
//   * any out-of-chord/degenerate sample lands on cols/rows {76,77} or {222,223},
//     which are all-zero for E (support [82,218)) and A (support [78,222)) -> its
//     weighted contribution is exactly 0; all addresses in-bounds by construction.
__global__ void __launch_bounds__(256, 4)
k_radon(const uint2* __restrict__ P, float* __restrict__ S) {
  __shared__ uint4 sLds[2][16 * 17];    // [buf][jrow*17 + u]; 17-stride kills write conflicts

  int t = threadIdx.x;
  int b    = t & 15;                    // consume: batch lane ; stage: i-offset
  int jrow = t >> 4;                    // 0..15
  int j  = blockIdx.x * 16 + jrow;
  int a  = blockIdx.y;
  if (j >= NDET) return;                // kills exactly wave 3 of block 18 (j 300..303)

  float th = (float)a * (float)(3.14159265358979323846 / 299.0);
  float cth = cosf(th), sth = sinf(th);
  float xj = fmaf((float)j, (float)(2.0 / 299.0), -1.0f);
  float pb = fmaf(cth,  xj, 1.0f) * 149.5f - 149.5f * sth;
  float qb = fmaf(-sth, xj, 1.0f) * 149.5f - 149.5f * cth;
  const float L = 76.5f, H = 222.5f;
  float lo = 0.f, hi = 299.0f;
  if (sth > 1e-6f) {
    float inv = 1.0f / sth;
    lo = fmaxf(lo, (L - pb) * inv); hi = fminf(hi, (H - pb) * inv);
  } else if (pb < L || pb > H) { hi = -1.f; }
  if (fabsf(cth) > 1e-6f) {
    float inv = 1.0f / cth;
    float t0 = (L - qb) * inv, t1 = (H - qb) * inv;
    lo = fmaxf(lo, fminf(t0, t1)); hi = fminf(hi, fmaxf(t0, t1));
  } else if (qb < L || qb > H) { hi = -1.f; }

  // wave-uniform union bounds over the 4 j's in this wave (empty chords give
  // lo=0, hi=-1 and contribute nothing; all-empty wave skips the loop)
  float lo_w = fminf(lo, __shfl_xor(lo, 16));
  lo_w = fminf(lo_w, __shfl_xor(lo_w, 32));
  float hi_w = fmaxf(hi, __shfl_xor(hi, 16));
  hi_w = fmaxf(hi_w, __shfl_xor(hi_w, 32));
  int i0w  = __builtin_amdgcn_readfirstlane((int)floorf(fmaxf(lo_w, 0.f)));
  int ihiw = __builtin_amdgcn_readfirstlane((int)floorf(hi_w));

  float sE0 = 0.f, sE1 = 0.f, sA0 = 0.f, sA1 = 0.f;

  if (ihiw >= i0w) {
    uint4* entW0 = &sLds[0][jrow * 17 + b];
    uint4* entW1 = &sLds[1][jrow * 17 + b];
    const uint4* entR0 = &sLds[0][jrow * 17];
    const uint4* entR1 = &sLds[1][jrow * 17];
    const char* P0 = (const char*)P;          // uniform base, row y0
    const char* P1 = P0 + WB * NB * 8;        // uniform base, row y0+1 (+18944 B)
    unsigned b8 = (unsigned)(b * 8);

    // voff = ((y0*148 + x0) - 76*149) * 128  (>= 0; canvas byte offset of row y0, batch 0)
    auto stage = [&](float fi, uint4* dst) {
      float px = fmaf(fi, sth, pb);
      float py = fmaf(fi, cth, qb);
      px = fminf(fmaxf(px, 76.5f), 222.0f);   // exact-zero clamp (see header)
      py = fminf(fmaxf(py, 76.5f), 222.0f);
      float x0f = floorf(px), y0f = floorf(py);
      float wx = px - x0f, wy = py - y0f;
      int idx = (int)fmaf(y0f, (float)WB, x0f);
      unsigned off = (unsigned)((idx - 76 * 149) << 7);   // pixel stride 128 B
      float omx = 1.0f - wx, omy = 1.0f - wy;
      unsigned w0 = pk16u(omy * omx, omy * wx);
      unsigned w1 = pk16u(wy * omx,  wy * wx);
      *dst = make_uint4(off, w0, w1, 0u);
    };

    auto consume = [&](const uint4* src) {
#pragma unroll
      for (int g = 0; g < 2; ++g) {
        uint4 e[8];
#pragma unroll
        for (int u = 0; u < 8; ++u) e[u] = src[g * 8 + u];   // broadcast reads
        unsigned vo[8];
#pragma unroll
        for (int u = 0; u < 8; ++u) vo[u] = e[u].x + b8;
        uint2 q0[8], q1[8];
#pragma unroll
        for (int u = 0; u < 8; ++u) {
          q0[u] = *(const uint2*)(P0 + vo[u]);               // row y0: {E pair, A pair}
          q1[u] = *(const uint2*)(P1 + vo[u]);               // row y0+1
        }
#pragma unroll
        for (int u = 0; u < 8; ++u) {
          sE0 = fdot2(q0[u].x, e[u].y, sE0);
          sE1 = fdot2(q1[u].x, e[u].z, sE1);
          sA0 = fdot2(q0[u].y, e[u].y, sA0);
          sA1 = fdot2(q1[u].y, e[u].z, sA1);
        }
      }
    };

    // Software pipeline: stage chunk k+1, then consume chunk k. LDS ops are
    // in-order within a wave, and the conservative LDS aliasing keeps the
    // write(k+1) ahead of its read one iteration later; no HW sync needed.
    float fi = (float)i0w + (float)b;
    int ib = i0w;
    stage(fi, entW0);
    for (;;) {
      bool more = (ib + 16 <= ihiw);          // wave-uniform
      if (more) stage(fi + 16.f, entW1);
      consume(entR0);
      if (!more) break;
      ib += 16; fi += 16.f;
      more = (ib + 16 <= ihiw);
      if (more) stage(fi + 16.f, entW0);
      consume(entR1);
      if (!more) break;
      ib += 16; fi += 16.f;
    }
  }

  float sumE = sE0 + sE1, sumA = sA0 + sA1;
  S[(a * NB + b) * NDET + j] = sumE * expf(-2.0f * sumA);  // VOXEL_MM = 2; layout [a][b][j]
}

// K3: per-angle 5-tap detector blur (reflect) + scale. S is [a][b][j] -> fully
// coalesced reads along j; out [b][a][j] coalesced writes.
__global__ void k_dblur(const float* __restrict__ S, const float* __restrict__ scale,
                        float* __restrict__ out) {
  int j = threadIdx.x;
  int a = blockIdx.x;
  int b = blockIdx.y;
  if (j >= NDET) return;
  float th = (float)a * (float)(3.14159265358979323846 / 299.0);
  float c = cosf(th), s = sinf(th);
  float u = fabsf(c) + fabsf(s);          // bw = 2u
  float u2 = u * u;
  float e1 = exp2f(-2.0f * u2);
  float e2 = exp2f(-8.0f * u2);
  float norm = 1.0f / (1.0f + 2.0f * (e1 + e2));
  float w2c = norm, w1c = e1 * norm, w0c = e2 * norm;
  const float* row = S + (a * NB + b) * NDET;
  float acc = 0.f;
#pragma unroll
  for (int tt = -2; tt <= 2; ++tt) {
    int jr = j + tt;
    if (jr < 0) jr = -jr;
    if (jr > 299) jr = 598 - jr;
    float w = (tt == 0) ? w2c : ((tt == 1 || tt == -1) ? w1c : w0c);
    acc = fmaf(w, row[jr], acc);
  }
  out[(b * NANG + a) * NDET + j] = acc * scale[b];
}

extern "C" void kernel_launch(void* const* d_in, const int* in_sizes, int n_in,
                              void* d_out, int out_size, void* d_ws, size_t ws_size,
                              hipStream_t stream) {
  const float* img   = (const float*)d_in[0];
  const float* att   = (const float*)d_in[1];
  const float* scale = (const float*)d_in[2];
  float* out = (float*)d_out;
  float* ws  = (float*)d_ws;

  // ws layout (floats): Q 148*148*16 uint2 (2.80 MB) | S 300*300*16 f32 (5.76 MB)
  uint2*  Q  = (uint2*)ws;
  float*  S  = ws + 700928;

  k_prep <<<dim3(10, 10, NB), 256, 0, stream>>>(img, att, Q);
  k_radon<<<dim3(19, NANG),   256, 0, stream>>>(Q, S);
  k_dblur<<<dim3(NANG, NB),   320, 0, stream>>>(S, scale, out);
}

// Round 2
// 146.059 us; speedup vs baseline: 1.3047x; 1.3047x over previous
//
#include <hip/hip_runtime.h>
#include <hip/hip_fp16.h>
#include <math.h>

#define NB   16     // batch
#define IMG  128    // input image side
#define NANG 300
#define NDET 300
#define WB   148    // canvas live box: x,y in [76,224)

typedef _Float16 v2h __attribute__((ext_vector_type(2)));

// Gaussian taps: sigma_img -> 2^(-d^2/2); sigma_att -> 2^(-d^2/8). f64 normalize, f32 cast.
__device__ __constant__ float KE[9] = {
  (float)(0.00390625            / 3.0104144100214136),
  (float)(0.04419417382415922   / 3.0104144100214136),
  (float)(0.25                  / 3.0104144100214136),
  (float)(0.7071067811865476    / 3.0104144100214136),
  (float)(1.0                   / 3.0104144100214136),
  (float)(0.7071067811865476    / 3.0104144100214136),
  (float)(0.25                  / 3.0104144100214136),
  (float)(0.04419417382415922   / 3.0104144100214136),
  (float)(0.00390625            / 3.0104144100214136)
};
__device__ __constant__ float KA[17] = {
  (float)(0.00390625            / 6.019333926786741),
  (float)(0.014328188175072987  / 6.019333926786741),
  (float)(0.04419417382415922   / 6.019333926786741),
  (float)(0.11462550540058389   / 6.019333926786741),
  (float)(0.25                  / 6.019333926786741),
  (float)(0.4585020216023356    / 6.019333926786741),
  (float)(0.7071067811865476    / 6.019333926786741),
  (float)(0.9170040432046712    / 6.019333926786741),
  (float)(1.0                   / 6.019333926786741),
  (float)(0.9170040432046712    / 6.019333926786741),
  (float)(0.7071067811865476    / 6.019333926786741),
  (float)(0.4585020216023356    / 6.019333926786741),
  (float)(0.25                  / 6.019333926786741),
  (float)(0.11462550540058389   / 6.019333926786741),
  (float)(0.04419417382415922   / 6.019333926786741),
  (float)(0.014328188175072987  / 6.019333926786741),
  (float)(0.00390625            / 6.019333926786741)
};

__device__ __forceinline__ unsigned h16(float f) {
  return (unsigned)__half_as_ushort(__float2half_rn(f));
}
__device__ __forceinline__ unsigned pk16u(float a, float b) {
  return __builtin_bit_cast(unsigned, __builtin_amdgcn_cvt_pkrtz(a, b));
}
__device__ __forceinline__ float fdot2(unsigned q, unsigned w, float acc) {
  return __builtin_amdgcn_fdot2(__builtin_bit_cast(v2h, q), __builtin_bit_cast(v2h, w), acc, false);
}

// K1: fused pad+blur -> f16 quad canvas over the live box [76,224)^2, SPLIT INTO
// TWO BATCH-HALF CANVASES (b 0..7 and b 8..15) so each is 148*148*8*16B = 2.80 MB
// and fits a 4 MiB per-XCD L2 (the round-0 16-batch canvas was 5.6 MB -> HBM thrash).
// Qh[y'][x'][bl] = uint4{ E00|E01<<16, E10|E11<<16, A00|A01<<16, A10|A11<<16 }
// (f16 pairs; suffix (r,c) = (y+r, x+c); A pre-scaled 0.01). Whole 2x2 bilinear
// footprint of both images in ONE 16-B load for k_radon.
__global__ void k_prep(const float* __restrict__ img, const float* __restrict__ att,
                       uint4* __restrict__ Q) {
  __shared__ float sImg[25 * 25];
  __shared__ float sAtt[33 * 33];
  __shared__ float sEi[25 * 17];
  __shared__ float sAi[33 * 17];

  int tid = threadIdx.x;
  int tx = tid & 15, ty = tid >> 4;
  int X0 = blockIdx.x * 16;
  int Y0 = blockIdx.y * 16;
  int b  = blockIdx.z;
  const float* imb = img + b * IMG * IMG;
  const float* atb = att + b * IMG * IMG;
  for (int t = tid; t < 625; t += 256) {
    int r = t / 25, c = t - r * 25;
    int ir = Y0 - 14 + r, ic = X0 - 14 + c;
    bool v = (ir >= 0) & (ir < IMG) & (ic >= 0) & (ic < IMG);
    sImg[t] = v ? imb[ir * IMG + ic] : 0.f;
  }
  for (int t = tid; t < 1089; t += 256) {
    int r = t / 33, c = t - r * 33;
    int ir = Y0 - 18 + r, ic = X0 - 18 + c;
    bool v = (ir >= 0) & (ir < IMG) & (ic >= 0) & (ic < IMG);
    sAtt[t] = v ? atb[ir * IMG + ic] : 0.f;
  }
  __syncthreads();
  for (int t = tid; t < 425; t += 256) {
    int r = t / 17, c = t - r * 17;
    float acc = 0.f;
#pragma unroll
    for (int d = 0; d < 9; ++d) acc = fmaf(KE[d], sImg[r * 25 + c + d], acc);
    sEi[t] = acc;
  }
  for (int t = tid; t < 561; t += 256) {
    int r = t / 17, c = t - r * 17;
    float acc = 0.f;
#pragma unroll
    for (int d = 0; d < 17; ++d) acc = fmaf(KA[d], sAtt[r * 33 + c + d], acc);
    sAi[t] = acc;
  }
  __syncthreads();
  int xc = X0 + tx, yc = Y0 + ty;
  if (xc >= WB || yc >= WB) return;
  float E00 = 0.f, E01 = 0.f, E10 = 0.f, E11 = 0.f;
  float A00 = 0.f, A01 = 0.f, A10 = 0.f, A11 = 0.f;
#pragma unroll
  for (int d = 0; d < 9; ++d) {
    float k = KE[d];
    E00 = fmaf(k, sEi[(ty + d) * 17 + tx],     E00);
    E01 = fmaf(k, sEi[(ty + d) * 17 + tx + 1], E01);
    E10 = fmaf(k, sEi[(ty + 1 + d) * 17 + tx],     E10);
    E11 = fmaf(k, sEi[(ty + 1 + d) * 17 + tx + 1], E11);
  }
#pragma unroll
  for (int d = 0; d < 17; ++d) {
    float k = KA[d];
    A00 = fmaf(k, sAi[(ty + d) * 17 + tx],     A00);
    A01 = fmaf(k, sAi[(ty + d) * 17 + tx + 1], A01);
    A10 = fmaf(k, sAi[(ty + 1 + d) * 17 + tx],     A10);
    A11 = fmaf(k, sAi[(ty + 1 + d) * 17 + tx + 1], A11);
  }
  uint4 q;
  q.x = h16(E00) | (h16(E01) << 16);
  q.y = h16(E10) | (h16(E11) << 16);
  q.z = h16(0.01f * A00) | (h16(0.01f * A01) << 16);
  q.w = h16(0.01f * A10) | (h16(0.01f * A11) << 16);
  uint4* Qh = Q + (b >> 3) * (WB * WB * 8);
  Qh[(yc * WB + xc) * 8 + (b & 7)] = q;
}

// K2: radon with wave-local LDS coordinate pipeline over batch-half canvases.
// Grid (10, 300, 2): z = batch half (slowest-varying -> all half-0 blocks dispatch
// before half-1, so each XCD's L2 holds ONE 2.8 MB canvas at a time).
// Block 256 = 32 j x 8 b; wave = 8 j x 8 b. Per 8-sample chunk:
//   Phase A: each lane computes coords+weights for a DISTINCT (j, i) (its b-slot
//            acts as i-offset) -> {pixel_off, w0, w1} to per-wave LDS region.
//   Phase B: 8 u-steps: broadcast ds_read_b128 + addr add + ONE dwordx4 + 4 fdot2.
//            Each 8-lane b-group's load = one full 128-B line (8 batches x 16 B).
// Same dynamic VMEM instruction count as the round-0 kernel (1 dwordx4 / sample),
// but the gather now hits L2 instead of thrashing HBM.
// Coordinate clamp px,py -> [76.5, 222.0] BEFORE floor:
//   * identity for in-chord samples (exact);
//   * any out-of-chord/degenerate sample lands on cols/rows {76,77} or {222,223},
//     which are all-zero for E (support [82,218)) and A (support [78,222)) -> its
//     weighted contribution is exactly 0; all addresses in-bounds by construction.
// j >= 300 lanes DO NOT early-return (they'd corrupt the wave shfl union); they
// get an empty chord (hi=-1) and skip the store.
__global__ void __launch_bounds__(256)
k_radon(const uint4* __restrict__ P, float* __restrict__ S) {
  __shared__ uint4 sLds[32 * 9];        // row jrow*9 + u ; stride 9 -> conflict-free

  int t = threadIdx.x;
  int bh   = t & 7;                     // phase B: batch lane (within half) ; phase A: i-offset
  int jrow = t >> 3;                    // 0..31
  int j  = blockIdx.x * 32 + jrow;
  int a  = blockIdx.y;
  int half = blockIdx.z;

  float th = (float)a * (float)(3.14159265358979323846 / 299.0);
  float c = cosf(th), s = sinf(th);
  float xj = fmaf((float)j, (float)(2.0 / 299.0), -1.0f);
  float pb = fmaf(c,  xj, 1.0f) * 149.5f - 149.5f * s;
  float qb = fmaf(-s, xj, 1.0f) * 149.5f - 149.5f * c;
  const float L = 76.5f, H = 222.5f;
  float lo = 0.f, hi = 299.0f;
  if (s > 1e-6f) {
    float inv = 1.0f / s;
    lo = fmaxf(lo, (L - pb) * inv); hi = fminf(hi, (H - pb) * inv);
  } else if (pb < L || pb > H) { hi = -1.f; }
  if (fabsf(c) > 1e-6f) {
    float inv = 1.0f / c;
    float t0 = (L - qb) * inv, t1 = (H - qb) * inv;
    lo = fmaxf(lo, fminf(t0, t1)); hi = fminf(hi, fmaxf(t0, t1));
  } else if (qb < L || qb > H) { hi = -1.f; }
  if (j >= NDET) { lo = 0.f; hi = -1.f; }   // dead j: empty chord, stays in shfl

  // wave-uniform union bounds over the 8 j's in this wave (empty chords give
  // lo=0, hi=-1 and contribute nothing; all-empty wave skips the loop)
  float lo_w = fminf(lo, __shfl_xor(lo, 8));
  lo_w = fminf(lo_w, __shfl_xor(lo_w, 16));
  lo_w = fminf(lo_w, __shfl_xor(lo_w, 32));
  float hi_w = fmaxf(hi, __shfl_xor(hi, 8));
  hi_w = fmaxf(hi_w, __shfl_xor(hi_w, 16));
  hi_w = fmaxf(hi_w, __shfl_xor(hi_w, 32));
  int i0w  = __builtin_amdgcn_readfirstlane((int)floorf(fmaxf(lo_w, 0.f)));
  int ihiw = __builtin_amdgcn_readfirstlane((int)floorf(hi_w));

  uint4* entW = &sLds[jrow * 9 + bh];
  const uint4* entR = &sLds[jrow * 9];

  const char* Pc = (const char*)(P + half * (WB * WB * 8));
  const char* Pcb = Pc + bh * 16;
  const int PIXBASE = -76 * 149 * 128;             // (y*148+x) -> box offset bias

  float sE0 = 0.f, sE1 = 0.f, sA0 = 0.f, sA1 = 0.f;
  float fib = (float)i0w + (float)bh;

  for (int ib = i0w; ib <= ihiw; ib += 8, fib += 8.f) {
    // Phase A: this lane computes sample (j, ib + bh)
    {
      float px = fmaf(fib, s, pb);
      float py = fmaf(fib, c, qb);
      px = fminf(fmaxf(px, 76.5f), 222.0f);        // exact-zero clamp (see header)
      py = fminf(fmaxf(py, 76.5f), 222.0f);
      float x0f = floorf(px), y0f = floorf(py);
      float wx = px - x0f, wy = py - y0f;
      int idx = (int)fmaf(y0f, (float)WB, x0f);
      int off = (idx << 7) + PIXBASE;              // pixel stride 128 B (8 batches)
      float omx = 1.0f - wx, omy = 1.0f - wy;
      unsigned w0 = pk16u(omy * omx, omy * wx);
      unsigned w1 = pk16u(wy * omx,  wy * wx);
      *entW = make_uint4((unsigned)off, w0, w1, w1);
    }
    __builtin_amdgcn_wave_barrier();
    // Phase B: consume 8 entries, 8 loads in flight
    {
      uint4 e[8];
#pragma unroll
      for (int u = 0; u < 8; ++u) e[u] = entR[u];  // broadcast reads
      uint4 q[8];
#pragma unroll
      for (int u = 0; u < 8; ++u)
        q[u] = *(const uint4*)(Pcb + (int)e[u].x);
#pragma unroll
      for (int u = 0; u < 8; ++u) {
        sE0 = fdot2(q[u].x, e[u].y, sE0);
        sE1 = fdot2(q[u].y, e[u].z, sE1);
        sA0 = fdot2(q[u].z, e[u].y, sA0);
        sA1 = fdot2(q[u].w, e[u].z, sA1);
      }
    }
    __builtin_amdgcn_wave_barrier();
  }
  float sumE = sE0 + sE1, sumA = sA0 + sA1;
  if (j < NDET) {
    int b = half * 8 + bh;
    S[(a * NB + b) * NDET + j] = sumE * expf(-2.0f * sumA);  // VOXEL_MM = 2; layout [a][b][j]
  }
}

// K3: per-angle 5-tap detector blur (reflect) + scale. S is [a][b][j] -> fully
// coalesced reads along j; out [b][a][j] coalesced writes.
__global__ void k_dblur(const float* __restrict__ S, const float* __restrict__ scale,
                        float* __restrict__ out) {
  int j = threadIdx.x;
  int a = blockIdx.x;
  int b = blockIdx.y;
  if (j >= NDET) return;
  float th = (float)a * (float)(3.14159265358979323846 / 299.0);
  float c = cosf(th), s = sinf(th);
  float u = fabsf(c) + fabsf(s);          // bw = 2u
  float u2 = u * u;
  float e1 = exp2f(-2.0f * u2);
  float e2 = exp2f(-8.0f * u2);
  float norm = 1.0f / (1.0f + 2.0f * (e1 + e2));
  float w2c = norm, w1c = e1 * norm, w0c = e2 * norm;
  const float* row = S + (a * NB + b) * NDET;
  float acc = 0.f;
#pragma unroll
  for (int tt = -2; tt <= 2; ++tt) {
    int jr = j + tt;
    if (jr < 0) jr = -jr;
    if (jr > 299) jr = 598 - jr;
    float w = (tt == 0) ? w2c : ((tt == 1 || tt == -1) ? w1c : w0c);
    acc = fmaf(w, row[jr], acc);
  }
  out[(b * NANG + a) * NDET + j] = acc * scale[b];
}

extern "C" void kernel_launch(void* const* d_in, const int* in_sizes, int n_in,
                              void* d_out, int out_size, void* d_ws, size_t ws_size,
                              hipStream_t stream) {
  const float* img   = (const float*)d_in[0];
  const float* att   = (const float*)d_in[1];
  const float* scale = (const float*)d_in[2];
  float* out = (float*)d_out;
  float* ws  = (float*)d_ws;

  // ws layout (floats): Q 2 x 148*148*8 uint4 (5.61 MB total) | S 300*300*16 f32 (5.76 MB)
  uint4*  Q  = (uint4*)ws;
  float*  S  = ws + 1401856;

  k_prep <<<dim3(10, 10, NB), 256, 0, stream>>>(img, att, Q);
  k_radon<<<dim3(10, NANG, 2), 256, 0, stream>>>(Q, S);
  k_dblur<<<dim3(NANG, NB),   320, 0, stream>>>(S, scale, out);
}

// Round 3
// 142.448 us; speedup vs baseline: 1.3378x; 1.0254x over previous
//
#include <hip/hip_runtime.h>
#include <hip/hip_fp16.h>
#include <math.h>

#define NB   16     // batch
#define IMG  128    // input image side
#define NANG 300
#define NDET 300
#define WB   148    // canvas live box: x,y in [76,224)

typedef _Float16 v2h __attribute__((ext_vector_type(2)));

// Gaussian taps: sigma_img -> 2^(-d^2/2); sigma_att -> 2^(-d^2/8). f64 normalize, f32 cast.
__device__ __constant__ float KE[9] = {
  (float)(0.00390625            / 3.0104144100214136),
  (float)(0.04419417382415922   / 3.0104144100214136),
  (float)(0.25                  / 3.0104144100214136),
  (float)(0.7071067811865476    / 3.0104144100214136),
  (float)(1.0                   / 3.0104144100214136),
  (float)(0.7071067811865476    / 3.0104144100214136),
  (float)(0.25                  / 3.0104144100214136),
  (float)(0.04419417382415922   / 3.0104144100214136),
  (float)(0.00390625            / 3.0104144100214136)
};
__device__ __constant__ float KA[17] = {
  (float)(0.00390625            / 6.019333926786741),
  (float)(0.014328188175072987  / 6.019333926786741),
  (float)(0.04419417382415922   / 6.019333926786741),
  (float)(0.11462550540058389   / 6.019333926786741),
  (float)(0.25                  / 6.019333926786741),
  (float)(0.4585020216023356    / 6.019333926786741),
  (float)(0.7071067811865476    / 6.019333926786741),
  (float)(0.9170040432046712    / 6.019333926786741),
  (float)(1.0                   / 6.019333926786741),
  (float)(0.9170040432046712    / 6.019333926786741),
  (float)(0.7071067811865476    / 6.019333926786741),
  (float)(0.4585020216023356    / 6.019333926786741),
  (float)(0.25                  / 6.019333926786741),
  (float)(0.11462550540058389   / 6.019333926786741),
  (float)(0.04419417382415922   / 6.019333926786741),
  (float)(0.014328188175072987  / 6.019333926786741),
  (float)(0.00390625            / 6.019333926786741)
};

__device__ __forceinline__ unsigned h16(float f) {
  return (unsigned)__half_as_ushort(__float2half_rn(f));
}
__device__ __forceinline__ unsigned pk16u(float a, float b) {
  return __builtin_bit_cast(unsigned, __builtin_amdgcn_cvt_pkrtz(a, b));
}
__device__ __forceinline__ float fdot2(unsigned q, unsigned w, float acc) {
  return __builtin_amdgcn_fdot2(__builtin_bit_cast(v2h, q), __builtin_bit_cast(v2h, w), acc, false);
}

// K1: fused pad+blur -> f16 quad canvas over the live box [76,224)^2, SPLIT INTO
// TWO BATCH-HALF CANVASES (b 0..7 and b 8..15) so each is 148*148*8*16B = 2.80 MB
// and fits a 4 MiB per-XCD L2.
// Qh[y'][x'][bl] = uint4{ E00|E01<<16, E10|E11<<16, A00|A01<<16, A10|A11<<16 }
// (f16 pairs; suffix (r,c) = (y+r, x+c); A pre-scaled 0.01). Whole 2x2 bilinear
// footprint of both images in ONE 16-B load for k_radon.
__global__ void k_prep(const float* __restrict__ img, const float* __restrict__ att,
                       uint4* __restrict__ Q) {
  __shared__ float sImg[25 * 25];
  __shared__ float sAtt[33 * 33];
  __shared__ float sEi[25 * 17];
  __shared__ float sAi[33 * 17];

  int tid = threadIdx.x;
  int tx = tid & 15, ty = tid >> 4;
  int X0 = blockIdx.x * 16;
  int Y0 = blockIdx.y * 16;
  int b  = blockIdx.z;
  const float* imb = img + b * IMG * IMG;
  const float* atb = att + b * IMG * IMG;
  for (int t = tid; t < 625; t += 256) {
    int r = t / 25, c = t - r * 25;
    int ir = Y0 - 14 + r, ic = X0 - 14 + c;
    bool v = (ir >= 0) & (ir < IMG) & (ic >= 0) & (ic < IMG);
    sImg[t] = v ? imb[ir * IMG + ic] : 0.f;
  }
  for (int t = tid; t < 1089; t += 256) {
    int r = t / 33, c = t - r * 33;
    int ir = Y0 - 18 + r, ic = X0 - 18 + c;
    bool v = (ir >= 0) & (ir < IMG) & (ic >= 0) & (ic < IMG);
    sAtt[t] = v ? atb[ir * IMG + ic] : 0.f;
  }
  __syncthreads();
  for (int t = tid; t < 425; t += 256) {
    int r = t / 17, c = t - r * 17;
    float acc = 0.f;
#pragma unroll
    for (int d = 0; d < 9; ++d) acc = fmaf(KE[d], sImg[r * 25 + c + d], acc);
    sEi[t] = acc;
  }
  for (int t = tid; t < 561; t += 256) {
    int r = t / 17, c = t - r * 17;
    float acc = 0.f;
#pragma unroll
    for (int d = 0; d < 17; ++d) acc = fmaf(KA[d], sAtt[r * 33 + c + d], acc);
    sAi[t] = acc;
  }
  __syncthreads();
  int xc = X0 + tx, yc = Y0 + ty;
  if (xc >= WB || yc >= WB) return;
  float E00 = 0.f, E01 = 0.f, E10 = 0.f, E11 = 0.f;
  float A00 = 0.f, A01 = 0.f, A10 = 0.f, A11 = 0.f;
#pragma unroll
  for (int d = 0; d < 9; ++d) {
    float k = KE[d];
    E00 = fmaf(k, sEi[(ty + d) * 17 + tx],     E00);
    E01 = fmaf(k, sEi[(ty + d) * 17 + tx + 1], E01);
    E10 = fmaf(k, sEi[(ty + 1 + d) * 17 + tx],     E10);
    E11 = fmaf(k, sEi[(ty + 1 + d) * 17 + tx + 1], E11);
  }
#pragma unroll
  for (int d = 0; d < 17; ++d) {
    float k = KA[d];
    A00 = fmaf(k, sAi[(ty + d) * 17 + tx],     A00);
    A01 = fmaf(k, sAi[(ty + d) * 17 + tx + 1], A01);
    A10 = fmaf(k, sAi[(ty + 1 + d) * 17 + tx],     A10);
    A11 = fmaf(k, sAi[(ty + 1 + d) * 17 + tx + 1], A11);
  }
  uint4 q;
  q.x = h16(E00) | (h16(E01) << 16);
  q.y = h16(E10) | (h16(E11) << 16);
  q.z = h16(0.01f * A00) | (h16(0.01f * A01) << 16);
  q.w = h16(0.01f * A10) | (h16(0.01f * A11) << 16);
  uint4* Qh = Q + (b >> 3) * (WB * WB * 8);
  Qh[(yc * WB + xc) * 8 + (b & 7)] = q;
}

// K2: radon over batch-half canvases, 16-deep software-pipelined gather.
// Grid (10, 300, 2): z = batch half (slowest-varying -> each XCD's L2 holds ONE
// 2.8 MB canvas at a time). Block 256 = 32 j x 8 b; wave = 8 j x 8 b.
// Per 16-sample SUPERCHUNK:
//   stage:   each lane computes coords+weights for TWO samples of its j
//            (i = base+bh and base+bh+8) -> {voff, w0, w1} into this chunk's LDS
//            buffer (double-buffered; next chunk staged while current consumes).
//   consume: 16 u-steps: broadcast ds_read_b128 + one v_add (32-bit voffset) +
//            ONE saddr-form global_load_dwordx4 (wave-uniform SGPR base) + 4 fdot2.
//            16 loads in flight per wave (2x the old 8) to cover the ~200-900 cy
//            L2/L3 gather latency; stage(k+1) VALU schedules under consume(k)'s
//            load shadow (no compiler fence between them; the single wave_barrier
//            per chunk only orders read(buf) before the NEXT write of that buf).
// Each 8-lane b-group's load = one full 128-B line (8 batches x 16 B).
// Coordinate clamp px,py -> [76.5, 222.0] BEFORE floor:
//   * identity for in-chord samples (exact);
//   * any out-of-chord/degenerate/overshoot sample (incl. superchunk tail padding)
//     lands on cols/rows {76,77} or {222,223}, all-zero for E (support [82,218))
//     and A (support [78,222)) -> exact-zero contribution; addresses in-bounds.
//   * chunk overshoot past i=299 is safe: chord exit t is strictly < 299 (box is
//     inside the sampling square's inscribed circle), so i>299 samples are always
//     out-of-box -> clamped to zero columns.
// j >= 300 lanes DO NOT early-return (they'd corrupt the wave shfl union); they
// get an empty chord (hi=-1) and skip the store.
__global__ void __launch_bounds__(256)
k_radon(const uint4* __restrict__ P, float* __restrict__ S) {
  __shared__ uint4 sLds[2][32 * 17];    // [buf][jrow*17 + u], u in 0..15; stride 17

  int t = threadIdx.x;
  int bh   = t & 7;                     // consume: batch lane (within half); stage: i-offset
  int jrow = t >> 3;                    // 0..31
  int j  = blockIdx.x * 32 + jrow;
  int a  = blockIdx.y;
  int half = blockIdx.z;

  float th = (float)a * (float)(3.14159265358979323846 / 299.0);
  float c = cosf(th), s = sinf(th);
  float xj = fmaf((float)j, (float)(2.0 / 299.0), -1.0f);
  float pb = fmaf(c,  xj, 1.0f) * 149.5f - 149.5f * s;
  float qb = fmaf(-s, xj, 1.0f) * 149.5f - 149.5f * c;
  const float L = 76.5f, H = 222.5f;
  float lo = 0.f, hi = 299.0f;
  if (s > 1e-6f) {
    float inv = 1.0f / s;
    lo = fmaxf(lo, (L - pb) * inv); hi = fminf(hi, (H - pb) * inv);
  } else if (pb < L || pb > H) { hi = -1.f; }
  if (fabsf(c) > 1e-6f) {
    float inv = 1.0f / c;
    float t0 = (L - qb) * inv, t1 = (H - qb) * inv;
    lo = fmaxf(lo, fminf(t0, t1)); hi = fminf(hi, fmaxf(t0, t1));
  } else if (qb < L || qb > H) { hi = -1.f; }
  if (j >= NDET) { lo = 0.f; hi = -1.f; }   // dead j: empty chord, stays in shfl

  // wave-uniform union bounds over the 8 j's in this wave
  float lo_w = fminf(lo, __shfl_xor(lo, 8));
  lo_w = fminf(lo_w, __shfl_xor(lo_w, 16));
  lo_w = fminf(lo_w, __shfl_xor(lo_w, 32));
  float hi_w = fmaxf(hi, __shfl_xor(hi, 8));
  hi_w = fmaxf(hi_w, __shfl_xor(hi_w, 16));
  hi_w = fmaxf(hi_w, __shfl_xor(hi_w, 32));
  int i0w  = __builtin_amdgcn_readfirstlane((int)floorf(fmaxf(lo_w, 0.f)));
  int ihiw = __builtin_amdgcn_readfirstlane((int)floorf(hi_w));

  float sE0 = 0.f, sE1 = 0.f, sA0 = 0.f, sA1 = 0.f;

  if (ihiw >= i0w) {
    uint4* row0 = &sLds[0][jrow * 17];
    uint4* row1 = &sLds[1][jrow * 17];
    const char* Pc = (const char*)(P + half * (WB * WB * 8));  // wave-uniform base
    unsigned b16 = (unsigned)(bh * 16);
    float fbh = (float)bh;

    // voff = ((y0*148 + x0) - 76*149) * 128  (>= 0; canvas byte offset, batch 0)
    auto stage1 = [&](float fi, uint4* dst) {
      float px = fmaf(fi, s, pb);
      float py = fmaf(fi, c, qb);
      px = fminf(fmaxf(px, 76.5f), 222.0f);        // exact-zero clamp (see header)
      py = fminf(fmaxf(py, 76.5f), 222.0f);
      float x0f = floorf(px), y0f = floorf(py);
      float wx = px - x0f, wy = py - y0f;
      int idx = (int)fmaf(y0f, (float)WB, x0f);
      unsigned off = (unsigned)((idx - 76 * 149) << 7);   // pixel stride 128 B
      float omx = 1.0f - wx, omy = 1.0f - wy;
      unsigned w0 = pk16u(omy * omx, omy * wx);
      unsigned w1 = pk16u(wy * omx,  wy * wx);
      *dst = make_uint4(off, w0, w1, 0u);
    };
    auto stage = [&](float fibase, uint4* row) {
      stage1(fibase + fbh,       row + bh);
      stage1(fibase + fbh + 8.f, row + bh + 8);
    };
    auto consume = [&](const uint4* src) {
      uint4 e[16];
#pragma unroll
      for (int u = 0; u < 16; ++u) e[u] = src[u];           // broadcast reads
      unsigned vo[16];
#pragma unroll
      for (int u = 0; u < 16; ++u) vo[u] = e[u].x + b16;
      uint4 q[16];
#pragma unroll
      for (int u = 0; u < 16; ++u)
        q[u] = *(const uint4*)(Pc + vo[u]);                 // saddr-form, 16 in flight
#pragma unroll
      for (int u = 0; u < 16; ++u) {
        sE0 = fdot2(q[u].x, e[u].y, sE0);
        sE1 = fdot2(q[u].y, e[u].z, sE1);
        sA0 = fdot2(q[u].z, e[u].y, sA0);
        sA1 = fdot2(q[u].w, e[u].z, sA1);
      }
    };

    // Pipeline: stage(k+1, other buf) overlaps consume(k). The wave_barrier sits
    // only between consume(buf) and the next stage into the SAME buf (per-wave
    // DS ops are in-order at the LDS unit; the fence stops compiler reordering).
    float f0 = (float)i0w;
    int ib = i0w;
    stage(f0, row0);
    for (;;) {
      bool more = (ib + 16 <= ihiw);          // wave-uniform
      if (more) stage(f0 + 16.f, row1);
      consume(row0);
      __builtin_amdgcn_wave_barrier();
      if (!more) break;
      ib += 16; f0 += 16.f;
      more = (ib + 16 <= ihiw);
      if (more) stage(f0 + 16.f, row0);
      consume(row1);
      __builtin_amdgcn_wave_barrier();
      if (!more) break;
      ib += 16; f0 += 16.f;
    }
  }

  float sumE = sE0 + sE1, sumA = sA0 + sA1;
  if (j < NDET) {
    int b = half * 8 + bh;
    S[(a * NB + b) * NDET + j] = sumE * expf(-2.0f * sumA);  // VOXEL_MM = 2; layout [a][b][j]
  }
}

// K3: per-angle 5-tap detector blur (reflect) + scale. S is [a][b][j] -> fully
// coalesced reads along j; out [b][a][j] coalesced writes.
__global__ void k_dblur(const float* __restrict__ S, const float* __restrict__ scale,
                        float* __restrict__ out) {
  int j = threadIdx.x;
  int a = blockIdx.x;
  int b = blockIdx.y;
  if (j >= NDET) return;
  float th = (float)a * (float)(3.14159265358979323846 / 299.0);
  float c = cosf(th), s = sinf(th);
  float u = fabsf(c) + fabsf(s);          // bw = 2u
  float u2 = u * u;
  float e1 = exp2f(-2.0f * u2);
  float e2 = exp2f(-8.0f * u2);
  float norm = 1.0f / (1.0f + 2.0f * (e1 + e2));
  float w2c = norm, w1c = e1 * norm, w0c = e2 * norm;
  const float* row = S + (a * NB + b) * NDET;
  float acc = 0.f;
#pragma unroll
  for (int tt = -2; tt <= 2; ++tt) {
    int jr = j + tt;
    if (jr < 0) jr = -jr;
    if (jr > 299) jr = 598 - jr;
    float w = (tt == 0) ? w2c : ((tt == 1 || tt == -1) ? w1c : w0c);
    acc = fmaf(w, row[jr], acc);
  }
  out[(b * NANG + a) * NDET + j] = acc * scale[b];
}

extern "C" void kernel_launch(void* const* d_in, const int* in_sizes, int n_in,
                              void* d_out, int out_size, void* d_ws, size_t ws_size,
                              hipStream_t stream) {
  const float* img   = (const float*)d_in[0];
  const float* att   = (const float*)d_in[1];
  const float* scale = (const float*)d_in[2];
  float* out = (float*)d_out;
  float* ws  = (float*)d_ws;

  // ws layout (floats): Q 2 x 148*148*8 uint4 (5.61 MB total) | S 300*300*16 f32 (5.76 MB)
  uint4*  Q  = (uint4*)ws;
  float*  S  = ws + 1401856;

  k_prep <<<dim3(10, 10, NB), 256, 0, stream>>>(img, att, Q);
  k_radon<<<dim3(10, NANG, 2), 256, 0, stream>>>(Q, S);
  k_dblur<<<dim3(NANG, NB),   320, 0, stream>>>(S, scale, out);
}